// Round 1
// baseline (167.799 us; speedup 1.0000x reference)
//
#include <hip/hip_runtime.h>

#define B_ 1024
#define T_ 256
#define C_ 100
#define L_ 64
#define NEG (-1e30f)
#define EPS_ 1e-7f

// logaddexp, safe for NEG sentinels (exp underflows to 0, no NaN)
__device__ __forceinline__ float lae(float a, float b) {
    float m = fmaxf(a, b);
    float n = fminf(a, b);
    return m + __logf(1.0f + __expf(n - m));
}

// One wave (64 lanes) per batch element.
// Lane i owns lattice states s0 = 2i (blank), s1 = 2i+1 (label i).
// Lane 63 additionally owns s2 = 128 (final blank).
// Blank states never use the skip transition, so the only cross-lane
// dependency per time step is old alpha[2i-1] = prev lane's s1 -> one shfl_up.
__global__ __launch_bounds__(64) void ctc_kernel(
    const int* __restrict__ y_true,
    const float* __restrict__ y_pred,
    float* __restrict__ out)
{
    const int b = blockIdx.x;
    const int lane = threadIdx.x;          // 0..63
    const int blank = C_ - 1;

    const float* __restrict__ base = y_pred + (size_t)b * T_ * C_;
    const int label   = y_true[b * L_ + lane];
    const int labprev = __shfl_up(label, 1);
    const bool allow  = (lane == 0) || (label != labprev);  // skip-transition mask for s1

    const float* __restrict__ pB = base + blank;   // blank column, uniform across wave
    const float* __restrict__ pL = base + label;   // this lane's label column

    // t = 0 init: only states 0 and 1 reachable (both in lane 0)
    const float lpb0 = __logf(pB[0] + EPS_);
    const float lpl0 = __logf(pL[0] + EPS_);
    float a0 = (lane == 0) ? lpb0 : NEG;
    float a1 = (lane == 0) ? lpl0 : NEG;
    float a2 = NEG;

    #pragma unroll 8
    for (int t = 1; t < T_; ++t) {
        const float xb = pB[t * C_];
        const float xl = pL[t * C_];
        const float nlpb = __logf(xb + EPS_);
        const float nlpl = __logf(xl + EPS_);

        float up1 = __shfl_up(a1, 1);              // old alpha[2i-1]
        up1 = (lane == 0) ? NEG : up1;

        const float n0 = lae(a0, up1) + nlpb;                          // blank: no skip
        const float n1 = lae(lae(a1, a0), allow ? up1 : NEG) + nlpl;   // label: optional skip
        const float n2 = lae(a2, a1) + nlpb;                           // state 128 (lane 63 local)

        a0 = n0; a1 = n1; a2 = n2;
    }

    if (lane == 63) {
        out[b] = -lae(a2, a1);   // -logaddexp(alpha[128], alpha[127])
    }
}

extern "C" void kernel_launch(void* const* d_in, const int* in_sizes, int n_in,
                              void* d_out, int out_size, void* d_ws, size_t ws_size,
                              hipStream_t stream) {
    const int*   y_true = (const int*)d_in[0];
    const float* y_pred = (const float*)d_in[1];
    float*       out    = (float*)d_out;

    ctc_kernel<<<dim3(B_), dim3(64), 0, stream>>>(y_true, y_pred, out);
}

// Round 3
// 93.503 us; speedup vs baseline: 1.7946x; 1.7946x over previous
//
#include <hip/hip_runtime.h>

#define B_ 1024
#define T_ 256
#define C_ 100
#define L_ 64
#define VEC 66              // padded row: 64 label lps + blank lp at [64]
#define NEG (-1e30f)
#define EPS_ 1e-7f
#define LN2 0.69314718055994530942f

#define EXP2(x) __builtin_amdgcn_exp2f(x)   // v_exp_f32: 2^x
#define LOG2(x) __builtin_amdgcn_logf(x)    // v_log_f32: log2(x)

// ---------------- kernel 1: gather + log2, massively parallel ----------------
// One wave per (b,t) row. lane l reads y_pred[b,t,label[b,l]]; lane 0 also the
// blank. Writes compact [B*T][VEC] f32 (coalesced 260B per wave).
__global__ __launch_bounds__(256) void gather_kernel(
    const int* __restrict__ y_true,
    const float* __restrict__ y_pred,
    float* __restrict__ gath)
{
    const int gid  = blockIdx.x * 4 + (threadIdx.x >> 6);   // row id = b*T + t
    const int lane = threadIdx.x & 63;
    const int b    = gid >> 8;                              // T_ == 256

    const float* __restrict__ row = y_pred + (size_t)gid * C_;
    const int label = y_true[b * L_ + lane];

    const float v = LOG2(row[label] + EPS_);
    float* __restrict__ orow = gath + (size_t)gid * VEC;
    orow[lane] = v;
    if (lane == 0) orow[64] = LOG2(row[C_ - 1] + EPS_);
}

// ---------------- kernel 2: DP over the compact lattice ----------------
// One wave per batch element. Lane i owns states {2i (blank), 2i+1 (label i)};
// lane 63 also state 128. One shfl_up per step. All in log2 space.
#define STEP(nlpb_, nlpl_) do {                                           \
    float up1 = __shfl_up(a1, 1);                                         \
    up1 = (lane == 0) ? NEG : up1;                                        \
    const float s  = allow ? up1 : NEG;                                   \
    const float m0 = fmaxf(a0, up1);                                      \
    const float t0 = EXP2(a0 - m0) + EXP2(up1 - m0);                      \
    const float m1 = fmaxf(fmaxf(a1, a0), s);                             \
    const float t1 = EXP2(a1 - m1) + EXP2(a0 - m1) + EXP2(s - m1);        \
    const float m2 = fmaxf(a2, a1);                                       \
    const float t2 = EXP2(a2 - m2) + EXP2(a1 - m2);                       \
    a0 = m0 + LOG2(t0) + (nlpb_);                                         \
    a1 = m1 + LOG2(t1) + (nlpl_);                                         \
    a2 = m2 + LOG2(t2) + (nlpb_);                                         \
} while (0)

__global__ __launch_bounds__(64) void dp_kernel(
    const int* __restrict__ y_true,
    const float* __restrict__ gath,
    float* __restrict__ out)
{
    const int b    = blockIdx.x;
    const int lane = threadIdx.x;
    const float* __restrict__ g = gath + (size_t)b * T_ * VEC;

    const int label   = y_true[b * L_ + lane];
    const int labprev = __shfl_up(label, 1);
    const bool allow  = (lane == 0) || (label != labprev);

    float cL[16], cB[16], nL[16], nB[16];

    // preload chunk 0 (t = 0..15) and chunk 1 (t = 16..31)
    #pragma unroll
    for (int j = 0; j < 16; ++j) {
        cL[j] = g[j * VEC + lane];
        cB[j] = g[j * VEC + 64];
    }
    #pragma unroll
    for (int j = 0; j < 16; ++j) {
        nL[j] = g[(16 + j) * VEC + lane];
        nB[j] = g[(16 + j) * VEC + 64];
    }

    // t = 0 init: only states 0,1 reachable (lane 0)
    float a0 = (lane == 0) ? cB[0] : NEG;
    float a1 = (lane == 0) ? cL[0] : NEG;
    float a2 = NEG;

    // rest of chunk 0: t = 1..15
    #pragma unroll
    for (int j = 1; j < 16; ++j) STEP(cB[j], cL[j]);

    // chunks 1..15, double-buffered: loads for c+1 issue before compute of c
    for (int c = 1; c < 16; ++c) {
        #pragma unroll
        for (int j = 0; j < 16; ++j) { cL[j] = nL[j]; cB[j] = nB[j]; }
        if (c < 15) {
            const int t0r = (c + 1) * 16;
            #pragma unroll
            for (int j = 0; j < 16; ++j) {
                nL[j] = g[(t0r + j) * VEC + lane];
                nB[j] = g[(t0r + j) * VEC + 64];
            }
        }
        #pragma unroll
        for (int j = 0; j < 16; ++j) STEP(cB[j], cL[j]);
    }

    if (lane == 63) {
        const float m = fmaxf(a2, a1);
        const float r = m + LOG2(EXP2(a2 - m) + EXP2(a1 - m));
        out[b] = -LN2 * r;     // convert log2 -> ln
    }
}

extern "C" void kernel_launch(void* const* d_in, const int* in_sizes, int n_in,
                              void* d_out, int out_size, void* d_ws, size_t ws_size,
                              hipStream_t stream) {
    const int*   y_true = (const int*)d_in[0];
    const float* y_pred = (const float*)d_in[1];
    float*       out    = (float*)d_out;
    float*       gath   = (float*)d_ws;   // needs B*T*VEC*4 = 69.2 MB

    gather_kernel<<<dim3(B_ * T_ / 4), dim3(256), 0, stream>>>(y_true, y_pred, gath);
    dp_kernel<<<dim3(B_), dim3(64), 0, stream>>>(y_true, gath, out);
}

// Round 4
// 80.535 us; speedup vs baseline: 2.0836x; 1.1610x over previous
//
#include <hip/hip_runtime.h>

#define B_ 1024
#define T_ 256
#define C_ 100
#define L_ 64
#define NEG (-1e30f)
#define EPS_ 1e-7f
#define LN2 0.69314718055994530942f

#define EXP2(x) __builtin_amdgcn_exp2f(x)   // v_exp_f32: 2^x
#define LOG2(x) __builtin_amdgcn_logf(x)    // v_log_f32: log2(x)

// Intermediate layouts (all f32, in d_ws):
//   gath : [B][16 chunks][64 lanes][16 t]  (64 MB) - lane l's label log2-prob for
//          t = chunk*16 + j, stored contiguously per (chunk,lane) -> float4-able
//   blank: [B][256]                        (1 MB)  - blank log2-prob per t
#define GATH_ELEMS ((size_t)B_ * 16 * 64 * 16)

// ---------------- kernel 1: gather + log2 ----------------
// One 1024-thread block per b. Thread (chunk=tid>>6, lane=tid&63) gathers its
// label's prob at 16 consecutive t (16 independent loads, ILP=16), stores 64B
// contiguous (4x dwordx4). First 256 threads also produce the blank column.
__global__ __launch_bounds__(1024) void gather_kernel(
    const int* __restrict__ y_true,
    const float* __restrict__ y_pred,
    float* __restrict__ gath,
    float* __restrict__ blankp)
{
    const int b     = blockIdx.x;
    const int tid   = threadIdx.x;
    const int lane  = tid & 63;
    const int chunk = tid >> 6;          // 0..15

    const float* __restrict__ base = y_pred + (size_t)b * T_ * C_;
    const int label = y_true[b * L_ + lane];

    float v[16];
    #pragma unroll
    for (int j = 0; j < 16; ++j)
        v[j] = LOG2(base[(chunk * 16 + j) * C_ + label] + EPS_);

    float* __restrict__ orow = gath + (((size_t)b * 16 + chunk) * 64 + lane) * 16;
    #pragma unroll
    for (int q = 0; q < 4; ++q)
        *reinterpret_cast<float4*>(orow + 4 * q) =
            make_float4(v[4*q], v[4*q+1], v[4*q+2], v[4*q+3]);

    if (tid < T_)
        blankp[b * T_ + tid] = LOG2(base[tid * C_ + (C_ - 1)] + EPS_);
}

// ---------------- kernel 2: DP over the compact lattice ----------------
// One wave per b. Lane i owns states {2i (blank), 2i+1 (label i)}; lane 63
// also state 128. One shfl_up per step. Log2 space throughout.
#define STEP(nlpb_, nlpl_) do {                                           \
    float up1 = __shfl_up(a1, 1);                                         \
    up1 = (lane == 0) ? NEG : up1;                                        \
    const float s  = allow ? up1 : NEG;                                   \
    const float m0 = fmaxf(a0, up1);                                      \
    const float t0 = EXP2(a0 - m0) + EXP2(up1 - m0);                      \
    const float m1 = fmaxf(fmaxf(a1, a0), s);                             \
    const float t1 = EXP2(a1 - m1) + EXP2(a0 - m1) + EXP2(s - m1);        \
    const float m2 = fmaxf(a2, a1);                                       \
    const float t2 = EXP2(a2 - m2) + EXP2(a1 - m2);                       \
    a0 = m0 + LOG2(t0) + (nlpb_);                                         \
    a1 = m1 + LOG2(t1) + (nlpl_);                                         \
    a2 = m2 + LOG2(t2) + (nlpb_);                                         \
} while (0)

#define LOADCHUNK(c_, L_arr, B_arr) do {                                  \
    const float* __restrict__ gc = gbase + (c_) * 1024;                   \
    const float* __restrict__ bc = bbase + (c_) * 16;                     \
    _Pragma("unroll")                                                     \
    for (int q = 0; q < 4; ++q) {                                         \
        const float4 f  = *reinterpret_cast<const float4*>(gc + 4 * q);   \
        const float4 fb = *reinterpret_cast<const float4*>(bc + 4 * q);   \
        L_arr[4*q]   = f.x;  L_arr[4*q+1] = f.y;                          \
        L_arr[4*q+2] = f.z;  L_arr[4*q+3] = f.w;                          \
        B_arr[4*q]   = fb.x; B_arr[4*q+1] = fb.y;                         \
        B_arr[4*q+2] = fb.z; B_arr[4*q+3] = fb.w;                         \
    }                                                                     \
} while (0)

__global__ __launch_bounds__(64) void dp_kernel(
    const int* __restrict__ y_true,
    const float* __restrict__ gath,
    const float* __restrict__ blankp,
    float* __restrict__ out)
{
    const int b    = blockIdx.x;
    const int lane = threadIdx.x;

    const float* __restrict__ gbase = gath + (size_t)b * 16384 + lane * 16;
    const float* __restrict__ bbase = blankp + b * T_;

    const int label   = y_true[b * L_ + lane];
    const int labprev = __shfl_up(label, 1);
    const bool allow  = (lane == 0) || (label != labprev);

    float cL[16], cB[16], nL[16], nB[16];

    LOADCHUNK(0, cL, cB);
    LOADCHUNK(1, nL, nB);

    // t = 0 init: only states 0,1 reachable (lane 0)
    float a0 = (lane == 0) ? cB[0] : NEG;
    float a1 = (lane == 0) ? cL[0] : NEG;
    float a2 = NEG;

    #pragma unroll
    for (int j = 1; j < 16; ++j) STEP(cB[j], cL[j]);

    for (int c = 1; c < 16; ++c) {
        #pragma unroll
        for (int j = 0; j < 16; ++j) { cL[j] = nL[j]; cB[j] = nB[j]; }
        if (c < 15) LOADCHUNK(c + 1, nL, nB);
        #pragma unroll
        for (int j = 0; j < 16; ++j) STEP(cB[j], cL[j]);
    }

    if (lane == 63) {
        const float m = fmaxf(a2, a1);
        const float r = m + LOG2(EXP2(a2 - m) + EXP2(a1 - m));
        out[b] = -LN2 * r;     // log2 -> ln
    }
}

extern "C" void kernel_launch(void* const* d_in, const int* in_sizes, int n_in,
                              void* d_out, int out_size, void* d_ws, size_t ws_size,
                              hipStream_t stream) {
    const int*   y_true = (const int*)d_in[0];
    const float* y_pred = (const float*)d_in[1];
    float*       out    = (float*)d_out;
    float*       gath   = (float*)d_ws;                 // 64 MB
    float*       blankp = (float*)d_ws + GATH_ELEMS;    // +1 MB

    gather_kernel<<<dim3(B_), dim3(1024), 0, stream>>>(y_true, y_pred, gath, blankp);
    dp_kernel<<<dim3(B_), dim3(64), 0, stream>>>(y_true, gath, blankp, out);
}

// Round 5
// 74.486 us; speedup vs baseline: 2.2528x; 1.0812x over previous
//
#include <hip/hip_runtime.h>

#define B_ 1024
#define T_ 256
#define C_ 100
#define L_ 64
#define NEG (-1e30f)
#define EPS_ 1e-7f
#define LN2 0.69314718055994530942f

#define EXP2(x) __builtin_amdgcn_exp2f(x)   // v_exp_f32: 2^x
#define LOG2(x) __builtin_amdgcn_logf(x)    // v_log_f32: log2(x)

#define ROWP 66   // LDS row: 64 label lps + blank at [64] (+1 pad) -> 2-way bank alias only

// One block of 1024 threads per batch element.
// Phase 1: all 16 waves gather log2-probs for the lattice into LDS [T][ROWP].
// Phase 2: wave 0 runs the 255-step CTC DP from LDS; other waves retire.
// Lane i owns states {2i (blank), 2i+1 (label i)}; lane 63 also state 128.
// Only cross-lane dep per step: prev lane's odd-state alpha -> one shfl_up.
#define STEP(nlpb_, nlpl_) do {                                           \
    float up1 = __shfl_up(a1, 1);                                         \
    up1 = (lane == 0) ? NEG : up1;                                        \
    const float s  = allow ? up1 : NEG;                                   \
    const float m0 = fmaxf(a0, up1);                                      \
    const float t0 = EXP2(a0 - m0) + EXP2(up1 - m0);                      \
    const float m1 = fmaxf(fmaxf(a1, a0), s);                             \
    const float t1 = EXP2(a1 - m1) + EXP2(a0 - m1) + EXP2(s - m1);        \
    const float m2 = fmaxf(a2, a1);                                       \
    const float t2 = EXP2(a2 - m2) + EXP2(a1 - m2);                       \
    a0 = m0 + LOG2(t0) + (nlpb_);                                         \
    a1 = m1 + LOG2(t1) + (nlpl_);                                         \
    a2 = m2 + LOG2(t2) + (nlpb_);                                         \
} while (0)

#define LOADCHUNK(c_, L_arr, B_arr) do {                                  \
    _Pragma("unroll")                                                     \
    for (int j = 0; j < 16; ++j) {                                        \
        L_arr[j] = lds[((c_) * 16 + j) * ROWP + lane];                    \
        B_arr[j] = lds[((c_) * 16 + j) * ROWP + 64];                      \
    }                                                                     \
} while (0)

__global__ __launch_bounds__(1024) void ctc_fused(
    const int* __restrict__ y_true,
    const float* __restrict__ y_pred,
    float* __restrict__ out)
{
    __shared__ float lds[T_ * ROWP];   // 67.6 KB -> 2 blocks/CU

    const int b     = blockIdx.x;
    const int tid   = threadIdx.x;
    const int lane  = tid & 63;
    const int chunk = tid >> 6;        // 0..15

    const float* __restrict__ base = y_pred + (size_t)b * T_ * C_;
    const int label = y_true[b * L_ + lane];

    // ---- phase 1: gather + log2 into LDS (16 independent loads / thread) ----
    float v[16];
    #pragma unroll
    for (int j = 0; j < 16; ++j)
        v[j] = base[(chunk * 16 + j) * C_ + label];
    #pragma unroll
    for (int j = 0; j < 16; ++j)
        lds[(chunk * 16 + j) * ROWP + lane] = LOG2(v[j] + EPS_);

    if (tid < T_)
        lds[tid * ROWP + 64] = LOG2(base[tid * C_ + (C_ - 1)] + EPS_);

    __syncthreads();

    if (tid >= 64) return;             // waves 1..15 done

    // ---- phase 2: DP by wave 0, all data in LDS ----
    const int labprev = __shfl_up(label, 1);
    const bool allow  = (lane == 0) || (label != labprev);

    float cL[16], cB[16], nL[16], nB[16];

    LOADCHUNK(0, cL, cB);
    LOADCHUNK(1, nL, nB);

    // t = 0 init: only states 0 (blank) and 1 (first label) reachable (lane 0)
    float a0 = (lane == 0) ? cB[0] : NEG;
    float a1 = (lane == 0) ? cL[0] : NEG;
    float a2 = NEG;

    #pragma unroll
    for (int j = 1; j < 16; ++j) STEP(cB[j], cL[j]);

    for (int c = 1; c < 16; ++c) {
        #pragma unroll
        for (int j = 0; j < 16; ++j) { cL[j] = nL[j]; cB[j] = nB[j]; }
        if (c < 15) LOADCHUNK(c + 1, nL, nB);
        #pragma unroll
        for (int j = 0; j < 16; ++j) STEP(cB[j], cL[j]);
    }

    if (lane == 63) {
        const float m = fmaxf(a2, a1);
        const float r = m + LOG2(EXP2(a2 - m) + EXP2(a1 - m));
        out[b] = -LN2 * r;             // log2 -> ln
    }
}

extern "C" void kernel_launch(void* const* d_in, const int* in_sizes, int n_in,
                              void* d_out, int out_size, void* d_ws, size_t ws_size,
                              hipStream_t stream) {
    const int*   y_true = (const int*)d_in[0];
    const float* y_pred = (const float*)d_in[1];
    float*       out    = (float*)d_out;

    ctc_fused<<<dim3(B_), dim3(1024), 0, stream>>>(y_true, y_pred, out);
}

// Round 6
// 53.163 us; speedup vs baseline: 3.1563x; 1.4011x over previous
//
#include <hip/hip_runtime.h>

#define B_ 1024
#define T_ 256
#define C_ 100
#define L_ 64
#define NEG (-1e30f)
#define EPS_ 1e-7f
#define LN2 0.69314718055994530942f

#define EXP2(x) __builtin_amdgcn_exp2f(x)   // v_exp_f32: 2^x
#define LOG2(x) __builtin_amdgcn_logf(x)    // v_log_f32: log2(x)

#define ROWP 66      // LDS row: 64 label lps + blank at [64] (+pad)
#define CH 32        // timestep window per buffer
#define NB 2         // batch elements per block
#define NCH (T_ / CH)          // 8 chunks
#define NBLK (B_ / NB)         // 512 blocks

// Producer/consumer fused CTC:
//   block = 1024 threads, owns NB=2 batch elements.
//   waves 0..1   : persistent DP waves (one per b), consume LDS window c
//   waves 2..15  : gather window c+1 (scattered y_pred reads + log2) into the
//                  other LDS buffer
//   one __syncthreads per 32-step window -> gather latency hides under DP.
// Lattice mapping (per DP wave): lane i owns states {2i (blank), 2i+1 (label)};
// lane 63 also state 128. One shfl_up per step is the only cross-lane dep.
#define STEP(nlpb_, nlpl_) do {                                           \
    float up1 = __shfl_up(a1, 1);                                         \
    up1 = (lane == 0) ? NEG : up1;                                        \
    const float s  = allow ? up1 : NEG;                                   \
    const float m0 = fmaxf(a0, up1);                                      \
    const float t0 = EXP2(a0 - m0) + EXP2(up1 - m0);                      \
    const float m1 = fmaxf(fmaxf(a1, a0), s);                             \
    const float t1 = EXP2(a1 - m1) + EXP2(a0 - m1) + EXP2(s - m1);        \
    const float m2 = fmaxf(a2, a1);                                       \
    const float t2 = EXP2(a2 - m2) + EXP2(a1 - m2);                       \
    a0 = m0 + LOG2(t0) + (nlpb_);                                         \
    a1 = m1 + LOG2(t1) + (nlpl_);                                         \
    a2 = m2 + LOG2(t2) + (nlpb_);                                         \
} while (0)

__global__ __launch_bounds__(1024) void ctc_fused(
    const int* __restrict__ y_true,
    const float* __restrict__ y_pred,
    float* __restrict__ out)
{
    __shared__ float buf[2][NB][CH][ROWP];   // 33.8 KB -> 2 blocks/CU

    const int tid  = threadIdx.x;
    const int lane = tid & 63;
    const int wave = tid >> 6;               // 0..15
    const int blk  = blockIdx.x;             // 0..511

    const float* __restrict__ p0 = y_pred + (size_t)(blk * NB + 0) * T_ * C_;
    const float* __restrict__ p1 = y_pred + (size_t)(blk * NB + 1) * T_ * C_;
    const int lab0 = y_true[(blk * NB + 0) * L_ + lane];
    const int lab1 = y_true[(blk * NB + 1) * L_ + lane];

    // ---- prologue: all 16 waves gather window 0 (rows = (b_local, t_local)) ----
    for (int r = wave; r < NB * CH; r += 16) {
        const int bl = r >> 5, tl = r & (CH - 1);
        const float* __restrict__ bp = bl ? p1 : p0;
        const int labx = bl ? lab1 : lab0;
        buf[0][bl][tl][lane] = LOG2(bp[tl * C_ + labx] + EPS_);
        if (lane == 0)
            buf[0][bl][tl][64] = LOG2(bp[tl * C_ + (C_ - 1)] + EPS_);
    }

    // DP-wave state
    const int   mylab   = wave ? lab1 : lab0;          // only used by waves 0,1
    const int   labprev = __shfl_up(mylab, 1);
    const bool  allow   = (lane == 0) || (mylab != labprev);
    float a0 = NEG, a1 = NEG, a2 = NEG;

    for (int c = 0; c < NCH; ++c) {
        __syncthreads();   // window c ready; buffer (c+1)&1 free

        if (wave >= NB) {
            // ---- producer: gather window c+1 into the other buffer ----
            if (c < NCH - 1) {
                float* __restrict__ dst = &buf[(c + 1) & 1][0][0][0];
                for (int r = wave - NB; r < NB * CH; r += 16 - NB) {
                    const int bl = r >> 5, tl = r & (CH - 1);
                    const int t  = (c + 1) * CH + tl;
                    const float* __restrict__ bp = bl ? p1 : p0;
                    const int labx = bl ? lab1 : lab0;
                    dst[(bl * CH + tl) * ROWP + lane] = LOG2(bp[t * C_ + labx] + EPS_);
                    if (lane == 0)
                        dst[(bl * CH + tl) * ROWP + 64] = LOG2(bp[t * C_ + (C_ - 1)] + EPS_);
                }
            }
        } else {
            // ---- consumer: advance DP over window c ----
            const float (*bb)[ROWP] = buf[c & 1][wave];
            int j0 = 0;
            if (c == 0) {
                // t = 0 init: only states 0 (blank) and 1 (first label), lane 0
                a0 = (lane == 0) ? bb[0][64] : NEG;
                a1 = (lane == 0) ? bb[0][0]  : NEG;
                a2 = NEG;
                j0 = 1;
            }
            #pragma unroll
            for (int j = 0; j < CH; ++j) {
                if (j < j0) continue;
                const float lpl = bb[j][lane];
                const float lpb = bb[j][64];
                STEP(lpb, lpl);
            }
        }
    }

    if (wave < NB && lane == 63) {
        const float m = fmaxf(a2, a1);
        const float r = m + LOG2(EXP2(a2 - m) + EXP2(a1 - m));
        out[blk * NB + wave] = -LN2 * r;   // log2 -> ln
    }
}

extern "C" void kernel_launch(void* const* d_in, const int* in_sizes, int n_in,
                              void* d_out, int out_size, void* d_ws, size_t ws_size,
                              hipStream_t stream) {
    const int*   y_true = (const int*)d_in[0];
    const float* y_pred = (const float*)d_in[1];
    float*       out    = (float*)d_out;

    ctc_fused<<<dim3(NBLK), dim3(1024), 0, stream>>>(y_true, y_pred, out);
}

// Round 7
// 51.852 us; speedup vs baseline: 3.2361x; 1.0253x over previous
//
#include <hip/hip_runtime.h>

#define B_ 1024
#define T_ 256
#define C_ 100
#define L_ 64
#define NEG (-1e30f)
#define EPS_ 1e-7f
#define LN2 0.69314718055994530942f

#define EXP2(x) __builtin_amdgcn_exp2f(x)   // v_exp_f32: 2^x
#define LOG2(x) __builtin_amdgcn_logf(x)    // v_log_f32: log2(x)

#define ROWP 66      // LDS row: 64 label lps + blank at [64] (+pad)
#define CH 32        // timestep window per buffer
#define NB 2         // batch elements per block
#define NCH (T_ / CH)          // 8 windows
#define NBLK (B_ / NB)         // 512 blocks
#define NPROD (16 - NB)        // 14 producer waves

// whole-wave shift-right-by-1 via DPP (gfx9 wave_shr:1 = 0x138).
// lane i gets x from lane i-1; lane 0 gets `fill` (bound_ctrl=false keeps old).
__device__ __forceinline__ float shr1_or(float x, float fill) {
    return __int_as_float(__builtin_amdgcn_update_dpp(
        __float_as_int(fill), __float_as_int(x), 0x138, 0xf, 0xf, false));
}

// One CTC DP step in log2 space. Lane i owns states {2i (blank), 2i+1 (label)};
// lane 63 also state 128 (a2). Only cross-lane dep: prev lane's a1 -> DPP.
#define STEP(nlpb_, nlpl_) do {                                           \
    const float up1 = shr1_or(a1, NEG);                                   \
    const float pm1 = fmaxf(a1, a0);                                      \
    const float s   = allow ? up1 : NEG;                                  \
    const float m0 = fmaxf(a0, up1);                                      \
    const float t0 = EXP2(a0 - m0) + EXP2(up1 - m0);                      \
    const float m1 = fmaxf(pm1, s);                                       \
    const float t1 = EXP2(a1 - m1) + EXP2(a0 - m1) + EXP2(s - m1);        \
    const float m2 = fmaxf(a2, a1);                                       \
    const float t2 = EXP2(a2 - m2) + EXP2(a1 - m2);                       \
    a0 = m0 + LOG2(t0) + (nlpb_);                                         \
    a1 = m1 + LOG2(t1) + (nlpl_);                                         \
    a2 = m2 + LOG2(t2) + (nlpb_);                                         \
} while (0)

// Producer/consumer fused CTC: block = 1024 threads = 16 waves, owns NB=2 b's.
// waves 0..1 consume LDS window c (DP); waves 2..15 gather window c+1.
__global__ __launch_bounds__(1024) void ctc_fused(
    const int* __restrict__ y_true,
    const float* __restrict__ y_pred,
    float* __restrict__ out)
{
    __shared__ float buf[2][NB][CH][ROWP];   // 33.8 KB -> 2 blocks/CU

    const int tid  = threadIdx.x;
    const int lane = tid & 63;
    const int wave = tid >> 6;               // 0..15
    const int blk  = blockIdx.x;             // 0..511

    const float* __restrict__ p0 = y_pred + (size_t)(blk * NB + 0) * T_ * C_;
    const float* __restrict__ p1 = y_pred + (size_t)(blk * NB + 1) * T_ * C_;
    const int lab0 = y_true[(blk * NB + 0) * L_ + lane];
    const int lab1 = y_true[(blk * NB + 1) * L_ + lane];

    // ---- prologue: all 16 waves gather window 0; 4 rows each, loads batched ----
    {
        float vl[4], vb[4];
        #pragma unroll
        for (int k = 0; k < 4; ++k) {
            const int r  = wave + 16 * k;            // 0..63, exact cover
            const int bl = r >> 5, tl = r & (CH - 1);
            const float* __restrict__ bp = bl ? p1 : p0;
            const int labx = bl ? lab1 : lab0;
            vl[k] = bp[tl * C_ + labx];
            vb[k] = bp[tl * C_ + (C_ - 1)];
        }
        #pragma unroll
        for (int k = 0; k < 4; ++k) {
            const int r  = wave + 16 * k;
            const int bl = r >> 5, tl = r & (CH - 1);
            buf[0][bl][tl][lane] = LOG2(vl[k] + EPS_);
            if (lane == 0) buf[0][bl][tl][64] = LOG2(vb[k] + EPS_);
        }
    }

    // DP-wave constants (harmless for producer waves)
    const int   mylab   = wave ? lab1 : lab0;
    const int   labprev = __shfl_up(mylab, 1);
    const bool  allow   = (lane == 0) || (mylab != labprev);
    float a0 = NEG, a1 = NEG, a2 = NEG;

    for (int c = 0; c < NCH; ++c) {
        __syncthreads();   // window c ready; buffer (c+1)&1 free

        if (wave >= NB) {
            // ---- producer: gather window c+1, loads batched (one latency) ----
            if (c < NCH - 1) {
                float* __restrict__ dst = &buf[(c + 1) & 1][0][0][0];
                const int base_r = wave - NB;        // 0..13
                float vl[5], vb[5];
                int   rr[5];
                #pragma unroll
                for (int k = 0; k < 5; ++k) {
                    const int r  = base_r + k * NPROD;
                    rr[k] = (r < NB * CH) ? r : -1;
                    const int r2 = (r < NB * CH) ? r : 0;     // safe clamp
                    const int bl = r2 >> 5, tl = r2 & (CH - 1);
                    const int t  = (c + 1) * CH + tl;
                    const float* __restrict__ bp = bl ? p1 : p0;
                    const int labx = bl ? lab1 : lab0;
                    vl[k] = bp[t * C_ + labx];
                    vb[k] = bp[t * C_ + (C_ - 1)];
                }
                #pragma unroll
                for (int k = 0; k < 5; ++k) {
                    if (rr[k] >= 0) {                         // wave-uniform
                        const int bl = rr[k] >> 5, tl = rr[k] & (CH - 1);
                        dst[(bl * CH + tl) * ROWP + lane] = LOG2(vl[k] + EPS_);
                        if (lane == 0)
                            dst[(bl * CH + tl) * ROWP + 64] = LOG2(vb[k] + EPS_);
                    }
                }
            }
        } else {
            // ---- consumer: advance DP over window c (clean unrolled loops) ----
            const float (*bb)[ROWP] = buf[c & 1][wave];
            if (c == 0) {
                // t = 0: only states 0 (blank) and 1 (first label), lane 0
                a0 = (lane == 0) ? bb[0][64] : NEG;
                a1 = (lane == 0) ? bb[0][0]  : NEG;
                a2 = NEG;
                #pragma unroll
                for (int j = 1; j < CH; ++j) STEP(bb[j][64], bb[j][lane]);
            } else {
                #pragma unroll
                for (int j = 0; j < CH; ++j) STEP(bb[j][64], bb[j][lane]);
            }
        }
    }

    if (wave < NB && lane == 63) {
        const float m = fmaxf(a2, a1);
        const float r = m + LOG2(EXP2(a2 - m) + EXP2(a1 - m));
        out[blk * NB + wave] = -LN2 * r;   // log2 -> ln
    }
}

extern "C" void kernel_launch(void* const* d_in, const int* in_sizes, int n_in,
                              void* d_out, int out_size, void* d_ws, size_t ws_size,
                              hipStream_t stream) {
    const int*   y_true = (const int*)d_in[0];
    const float* y_pred = (const float*)d_in[1];
    float*       out    = (float*)d_out;

    ctc_fused<<<dim3(NBLK), dim3(1024), 0, stream>>>(y_true, y_pred, out);
}

// Round 8
// 28.318 us; speedup vs baseline: 5.9255x; 1.8311x over previous
//
#include <hip/hip_runtime.h>

#define B_ 1024
#define T_ 256
#define C_ 100
#define L_ 64
#define EPS_ 1e-7f
#define LN2 0.69314718055994530942f

#define LOG2F(x) __builtin_amdgcn_logf(x)    // v_log_f32: log2(x)

// whole-wave shift-right-by-1 via DPP (gfx9 wave_shr:1 = 0x138); lane 0 <- 0.
__device__ __forceinline__ float dpp_shr1(float x) {
    return __int_as_float(__builtin_amdgcn_update_dpp(
        0, __float_as_int(x), 0x138, 0xf, 0xf, false));
}

// Linear-space CTC step. Lane i owns states {2i (blank), 2i+1 (label i)};
// lane 63 also state 128 (a2). alphas are probabilities (scaled); the only
// cross-lane dep is prev lane's a1 -> one DPP. 3 adds + 3 muls + 2 adds.
#define STEP(pb_, pl_) do {                                               \
    const float up1 = dpp_shr1(a1);                                       \
    const float s   = allow ? up1 : 0.0f;                                 \
    const float n0  = (a0 + up1) * (pb_);                                 \
    const float n1  = ((a1 + a0) + s) * (pl_);                            \
    const float n2  = (a2 + a1) * (pb_);                                  \
    a0 = n0; a1 = n1; a2 = n2;                                            \
} while (0)

// Plan a rescale: wave-max of current alphas -> scale 2^K lifting max to ~1.
// Applied one 8-step boundary later (stale -> butterfly latency fully hidden).
#define PLAN() do {                                                       \
    float m_ = fmaxf(fmaxf(a0, a1), a2);                                  \
    _Pragma("unroll")                                                     \
    for (int d_ = 1; d_ < 64; d_ <<= 1) m_ = fmaxf(m_, __shfl_xor(m_, d_)); \
    const int e_ = (__float_as_int(m_) >> 23) & 255;                      \
    rs_K = 127 - e_;                                                      \
    rs_scale = __int_as_float((254 - e_) << 23);  /* 2^(127-e) */         \
} while (0)

#define APPLY() do { a0 *= rs_scale; a1 *= rs_scale; a2 *= rs_scale;      \
                     Sacc += rs_K; } while (0)

// One wave per batch element; register double-buffered 16-step chunks.
__global__ __launch_bounds__(64) void ctc_kernel(
    const int* __restrict__ y_true,
    const float* __restrict__ y_pred,
    float* __restrict__ out)
{
    const int b    = blockIdx.x;
    const int lane = threadIdx.x;

    const float* __restrict__ base = y_pred + (size_t)b * T_ * C_;
    const int label   = y_true[b * L_ + lane];
    const int labprev = __shfl_up(label, 1);
    const bool allow  = (lane == 0) || (label != labprev);

    const float* __restrict__ pL = base + label;     // per-lane label column
    const float* __restrict__ pB = base + (C_ - 1);  // blank column (uniform)

    float pl[2][16], pb[2][16];

    // preload chunks 0 and 1 (32 loads in flight)
    #pragma unroll
    for (int k = 0; k < 16; ++k) { pl[0][k] = pL[k * C_];        pb[0][k] = pB[k * C_]; }
    #pragma unroll
    for (int k = 0; k < 16; ++k) { pl[1][k] = pL[(16 + k) * C_]; pb[1][k] = pB[(16 + k) * C_]; }

    float a0 = 0.0f, a1 = 0.0f, a2 = 0.0f;
    float rs_scale = 1.0f;
    int   rs_K = 0, Sacc = 0;

    #pragma unroll
    for (int c = 0; c < 16; ++c) {
        // prefetch chunk c+1 into the buffer freed by chunk c-1
        if (c >= 1 && c + 1 < 16) {
            #pragma unroll
            for (int k = 0; k < 16; ++k) {
                pl[(c + 1) & 1][k] = pL[((c + 1) * 16 + k) * C_];
                pb[(c + 1) & 1][k] = pB[((c + 1) * 16 + k) * C_];
            }
        }
        #pragma unroll
        for (int k = 0; k < 16; ++k) {
            if (c == 0 && k == 0) {
                // t = 0: only states 0 (blank) and 1 (first label), lane 0
                a0 = (lane == 0) ? (pb[0][0] + EPS_) : 0.0f;
                a1 = (lane == 0) ? (pl[0][0] + EPS_) : 0.0f;
                a2 = 0.0f;
                PLAN();                       // pending for t=8
            } else {
                if (k == 0 || k == 8) {       // 8-step boundary: t = c*16+k
                    APPLY();                  // stale scale (planned 8 ago)
                    PLAN();                   // plan for next boundary
                }
                STEP(pb[c & 1][k] + EPS_, pl[c & 1][k] + EPS_);
            }
        }
    }

    if (lane == 63) {
        // true alpha = stored * 2^(-Sacc);  loss = -ln(a127 + a128)
        out[b] = -LN2 * (LOG2F(a1 + a2) - (float)Sacc);
    }
}

extern "C" void kernel_launch(void* const* d_in, const int* in_sizes, int n_in,
                              void* d_out, int out_size, void* d_ws, size_t ws_size,
                              hipStream_t stream) {
    const int*   y_true = (const int*)d_in[0];
    const float* y_pred = (const float*)d_in[1];
    float*       out    = (float*)d_out;

    ctc_kernel<<<dim3(B_), dim3(64), 0, stream>>>(y_true, y_pred, out);
}

// Round 9
// 24.013 us; speedup vs baseline: 6.9879x; 1.1793x over previous
//
#include <hip/hip_runtime.h>

#define B_ 1024
#define T_ 256
#define C_ 100
#define L_ 64
#define EPS_ 1e-7f
#define LN2 0.69314718055994530942f

#define CH 8               // timesteps per chunk
#define NCH (T_ / CH)      // 32 chunks
#define DEPTH 3            // chunks in flight beyond current (27 loads max)

#define LOG2F(x) __builtin_amdgcn_logf(x)    // v_log_f32: log2(x)

typedef const __attribute__((address_space(1))) void GV;
typedef __attribute__((address_space(3))) void LV;

// async global->LDS, 4B per lane; LDS dest = uniform base + lane*4 (m104)
__device__ __forceinline__ void gload_lds4(const void* g, void* l) {
    __builtin_amdgcn_global_load_lds((GV*)g, (LV*)l, 4, 0, 0);
}

// whole-wave shift-right-by-1 via DPP (gfx9 wave_shr:1 = 0x138); lane 0 <- 0.
__device__ __forceinline__ float dpp_shr1(float x) {
    return __int_as_float(__builtin_amdgcn_update_dpp(
        0, __float_as_int(x), 0x138, 0xf, 0xf, false));
}

// Linear-space CTC step. Lane i owns states {2i (blank), 2i+1 (label i)};
// lane 63 also state 128 (a2). Only cross-lane dep: prev lane's a1 -> DPP.
#define STEP(pb_, pl_) do {                                               \
    const float up1 = dpp_shr1(a1);                                       \
    const float s   = allow ? up1 : 0.0f;                                 \
    const float n0  = (a0 + up1) * (pb_);                                 \
    const float n1  = ((a1 + a0) + s) * (pl_);                            \
    const float n2  = (a2 + a1) * (pb_);                                  \
    a0 = n0; a1 = n1; a2 = n2;                                            \
} while (0)

// Plan a rescale from the wave-max of current alphas (butterfly off the
// critical path); applied one 8-step boundary later (stale -> latency hidden).
#define PLAN() do {                                                       \
    float m_ = fmaxf(fmaxf(a0, a1), a2);                                  \
    _Pragma("unroll")                                                     \
    for (int d_ = 1; d_ < 64; d_ <<= 1) m_ = fmaxf(m_, __shfl_xor(m_, d_)); \
    const int e_ = (__float_as_int(m_) >> 23) & 255;                      \
    rs_K = 127 - e_;                                                      \
    rs_scale = __int_as_float((254 - e_) << 23);  /* 2^(127-e) */         \
} while (0)

#define APPLY() do { a0 *= rs_scale; a1 *= rs_scale; a2 *= rs_scale;      \
                     Sacc += rs_K; } while (0)

// Issue chunk c_: 8 per-lane label gathers + 1 packed blank load (lane k
// carries blank at t = c*CH + (k&7)) -> 9 VMEM ops per chunk.
#define ISSUE(c_) do {                                                    \
    const int bufi_ = (c_) & 3;                                           \
    _Pragma("unroll")                                                     \
    for (int j_ = 0; j_ < CH; ++j_)                                       \
        gload_lds4(pL + ((c_) * CH + j_) * C_, &plbuf[bufi_][j_][0]);     \
    gload_lds4(pBl + (c_) * CH * C_, &pbbuf[bufi_][0]);                   \
} while (0)

// One wave per batch element; LDS ring pipeline with counted vmcnt waits.
__global__ __launch_bounds__(64) void ctc_kernel(
    const int* __restrict__ y_true,
    const float* __restrict__ y_pred,
    float* __restrict__ out)
{
    __shared__ float plbuf[4][CH][64];   // 8 KB: label probs, lane-indexed
    __shared__ float pbbuf[4][64];       // 1 KB: blank probs (first 8 used)

    const int b    = blockIdx.x;
    const int lane = threadIdx.x;

    const float* __restrict__ base = y_pred + (size_t)b * T_ * C_;
    const int label   = y_true[b * L_ + lane];
    const int labprev = __shfl_up(label, 1);
    const bool allow  = (lane == 0) || (label != labprev);

    const float* __restrict__ pL  = base + label;                           // per-lane label col
    const float* __restrict__ pBl = base + (C_ - 1) + (lane & (CH - 1)) * C_; // blank, lane-packed

    ISSUE(0); ISSUE(1); ISSUE(2);        // 27 loads outstanding

    float a0 = 0.0f, a1 = 0.0f, a2 = 0.0f;
    float rs_scale = 1.0f;
    int   rs_K = 0, Sacc = 0;

    #pragma unroll
    for (int c = 0; c < NCH; ++c) {
        // wait for chunk c only: outstanding beyond c is 18 / 9 / 0 loads
        if (c <= NCH - 3)      { asm volatile("s_waitcnt vmcnt(18)" ::: "memory"); }
        else if (c == NCH - 2) { asm volatile("s_waitcnt vmcnt(9)"  ::: "memory"); }
        else                   { asm volatile("s_waitcnt vmcnt(0)"  ::: "memory"); }

        const int bufi = c & 3;
        if (c == 0) {
            // t = 0: only states 0 (blank) and 1 (first label), lane 0
            a0 = (lane == 0) ? (pbbuf[0][0] + EPS_) : 0.0f;
            a1 = (lane == 0) ? (plbuf[0][0][lane] + EPS_) : 0.0f;
            a2 = 0.0f;
            PLAN();                       // pending for t = 8
            #pragma unroll
            for (int j = 1; j < CH; ++j)
                STEP(pbbuf[bufi][j] + EPS_, plbuf[bufi][j][lane] + EPS_);
        } else {
            APPLY();                      // stale scale (planned 8 steps ago)
            PLAN();
            #pragma unroll
            for (int j = 0; j < CH; ++j)
                STEP(pbbuf[bufi][j] + EPS_, plbuf[bufi][j][lane] + EPS_);
        }

        if (c + DEPTH < NCH) ISSUE(c + DEPTH);
    }

    if (lane == 63) {
        // true alpha = stored * 2^(-Sacc);  loss = -ln(a127 + a128)
        out[b] = -LN2 * (LOG2F(a1 + a2) - (float)Sacc);
    }
}

extern "C" void kernel_launch(void* const* d_in, const int* in_sizes, int n_in,
                              void* d_out, int out_size, void* d_ws, size_t ws_size,
                              hipStream_t stream) {
    const int*   y_true = (const int*)d_in[0];
    const float* y_pred = (const float*)d_in[1];
    float*       out    = (float*)d_out;

    ctc_kernel<<<dim3(B_), dim3(64), 0, stream>>>(y_true, y_pred, out);
}